// Round 3
// baseline (292.315 us; speedup 1.0000x reference)
//
#include <hip/hip_runtime.h>
#include <hip/hip_bf16.h>

#define BB 4096
#define NNB 20
#define GG 4
#define DIN 128
#define EE 64
#define HH 8

__device__ __forceinline__ float lrelu_f(float x) { return x > 0.f ? x : 0.2f * x; }

// ---------------- K0: prep ----------------
__global__ __launch_bounds__(256) void prep_kernel(
    const float* __restrict__ W_heads, const float* __restrict__ a_self,
    const float* __restrict__ a_neigh, const float* __restrict__ W_out,
    float* __restrict__ w_neigh, float* __restrict__ w_self,
    float* __restrict__ Wt, float* __restrict__ Wot) {
  int id = blockIdx.x * 256 + threadIdx.x;
  if (id < 2048) {
    int sel = id >> 10;            // 0 -> neigh, 1 -> self
    int h = (id >> 7) & 7, d = id & 127;
    const float* a = sel ? a_self : a_neigh;
    const float* Wrow = W_heads + (h * DIN + d) * EE;
    float acc = 0.f;
    for (int e = 0; e < EE; ++e) acc = fmaf(Wrow[e], a[h * EE + e], acc);
    (sel ? w_self : w_neigh)[h * DIN + d] = acc;
  } else if (id < 2048 + 65536) {
    int rel = id - 2048;           // rel = (h*64+e)*128 + d
    int h = rel >> 13, e = (rel >> 7) & 63, d = rel & 127;
    Wt[rel] = W_heads[(h * DIN + d) * EE + e];
  } else if (id < 2048 + 65536 + 32768) {
    int rel = id - 2048 - 65536;   // rel = e*512 + k
    int e = rel >> 9, k = rel & 511;
    Wot[rel] = W_out[k * EE + e];
  }
}

// ---------------- K1: per-b fused f + softmax + agg (chunk-local agg) ----------------
__global__ __launch_bounds__(256) void attn_agg_kernel(
    const float* __restrict__ self_vecs, const float* __restrict__ neigh_vecs,
    const float* __restrict__ w_neigh, const float* __restrict__ w_self,
    __hip_bfloat16* __restrict__ agg /* [chunk*G][H][DIN] bf16 */, int b0) {
  __shared__ float x_s[80 * DIN];        // 40 KB, rows (n,g) linear
  __shared__ float f_s[84][8];           // rows 0..79 neigh, 80..83 self
  __shared__ float att_s[NNB * GG * HH]; // [n][g][h]

  const int bl = blockIdx.x;             // chunk-local b
  const int b = b0 + bl;                 // global b
  const int t = threadIdx.x;
  const float* nb = neigh_vecs + (size_t)b * (NNB * GG * DIN);

  // P0: stage neigh rows into LDS (linear, fully coalesced)
  for (int k = 0; k < 10; ++k) {
    int idx = t + 256 * k;               // float4 index, 2560 total
    ((float4*)x_s)[idx] = ((const float4*)nb)[idx];
  }

  // P1: f-dots. threads 0..167 -> (row, half). row<80: neigh row (n*4+g); 80..83: self row g.
  if (t < 168) {
    int row = t >> 1, q = t & 1;
    const float* xptr;
    const float* wptr;
    if (row < 80) { xptr = nb + row * DIN; wptr = w_neigh; }
    else          { xptr = self_vecs + ((size_t)b * GG + (row - 80)) * DIN; wptr = w_self; }
    float p[8] = {0.f, 0.f, 0.f, 0.f, 0.f, 0.f, 0.f, 0.f};
    const int base = q * 64;
    for (int j = 0; j < 16; ++j) {
      float4 x4 = *(const float4*)(xptr + base + 4 * j);
#pragma unroll
      for (int h = 0; h < 8; ++h) {
        float4 w4 = *(const float4*)(wptr + h * DIN + base + 4 * j);
        p[h] = fmaf(x4.x, w4.x, p[h]);
        p[h] = fmaf(x4.y, w4.y, p[h]);
        p[h] = fmaf(x4.z, w4.z, p[h]);
        p[h] = fmaf(x4.w, w4.w, p[h]);
      }
    }
#pragma unroll
    for (int h = 0; h < 8; ++h) p[h] += __shfl_xor(p[h], 1);
    if (q == 0) {
#pragma unroll
      for (int h = 0; h < 8; ++h) f_s[row][h] = p[h];
    }
  }
  __syncthreads();

  // P2: softmax over g for each (n,h). threads 0..159.
  if (t < 160) {
    int n = t >> 3, h = t & 7;
    float l[4], m = -1e30f;
#pragma unroll
    for (int g = 0; g < 4; ++g) {
      float v = lrelu_f(f_s[80 + g][h] + f_s[n * 4 + g][h]);
      l[g] = v;
      m = fmaxf(m, v);
    }
    float s = 0.f;
#pragma unroll
    for (int g = 0; g < 4; ++g) { l[g] = __expf(l[g] - m); s += l[g]; }
    float inv = 1.f / s;
#pragma unroll
    for (int g = 0; g < 4; ++g) att_s[(n * 4 + g) * 8 + h] = l[g] * inv;
  }
  __syncthreads();

  // P3: agg[g][h][d] = sum_n att[n][g][h] * x[n][g][d]; thread = (g, d-pair), all 8 h in regs.
  {
    int g = t >> 6, d2 = t & 63;     // wave-uniform g
    float acc[8][2];
#pragma unroll
    for (int h = 0; h < 8; ++h) { acc[h][0] = 0.f; acc[h][1] = 0.f; }
    for (int n = 0; n < NNB; ++n) {
      float2 x2 = *(const float2*)&x_s[(n * 4 + g) * DIN + d2 * 2];
#pragma unroll
      for (int h = 0; h < 8; ++h) {
        float a = att_s[(n * 4 + g) * 8 + h];
        acc[h][0] = fmaf(a, x2.x, acc[h][0]);
        acc[h][1] = fmaf(a, x2.y, acc[h][1]);
      }
    }
    // chunk-local row index
    __hip_bfloat16* ap = agg + ((size_t)(bl * GG + g) * HH) * DIN + d2 * 2;
#pragma unroll
    for (int h = 0; h < 8; ++h) {
      __hip_bfloat162 v2;
      v2.x = __float2bfloat16(acc[h][0]);
      v2.y = __float2bfloat16(acc[h][1]);
      *reinterpret_cast<__hip_bfloat162*>(ap + h * DIN) = v2;
    }
  }
}

// ---------------- K2: out_h matvec + final FC + relu, 8 rows per block ----------------
__global__ __launch_bounds__(256) void head_fc_kernel(
    const __hip_bfloat16* __restrict__ agg, const float* __restrict__ Wt,
    const float* __restrict__ Wot, float* __restrict__ out,
    int out_row_base /* = b0*G */) {
  __shared__ float agg_s[8 * 1024];  // 32 KB  [r][h*128+d] f32
  __shared__ float h_s[8 * 512];     // 16 KB  [r][k] f32

  const int t = threadIdx.x;
  const size_t row0l = (size_t)blockIdx.x * 8;   // chunk-local row

  // stage agg rows, bf16 -> f32
  const unsigned int* au = (const unsigned int*)(agg + row0l * HH * DIN); // 4096 uints
  for (int k = 0; k < 16; ++k) {
    int idx = t + 256 * k;
    unsigned int u = au[idx];
    float lo = __uint_as_float(u << 16);
    float hi = __uint_as_float(u & 0xffff0000u);
    ((float2*)agg_s)[idx] = make_float2(lo, hi);
  }
  __syncthreads();

  const int e = t & 63;
  const int h0 = t >> 6;   // wave-uniform
  // phase B: out_h[r][hh*64+e] = lrelu(sum_d agg[r][hh][d] * Wt[hh][e][d])
#pragma unroll
  for (int hi_ = 0; hi_ < 2; ++hi_) {
    int hh = h0 + 4 * hi_;
    float acc[8];
#pragma unroll
    for (int r = 0; r < 8; ++r) acc[r] = 0.f;
    const float4* wp = (const float4*)(Wt + (hh * 64 + e) * DIN);
    for (int d4 = 0; d4 < 32; ++d4) {
      float4 w4 = wp[d4];
#pragma unroll
      for (int r = 0; r < 8; ++r) {
        float4 x4 = ((const float4*)agg_s)[r * 256 + hh * 32 + d4];
        acc[r] = fmaf(w4.x, x4.x, acc[r]);
        acc[r] = fmaf(w4.y, x4.y, acc[r]);
        acc[r] = fmaf(w4.z, x4.z, acc[r]);
        acc[r] = fmaf(w4.w, x4.w, acc[r]);
      }
    }
#pragma unroll
    for (int r = 0; r < 8; ++r) h_s[r * 512 + hh * 64 + e] = lrelu_f(acc[r]);
  }
  __syncthreads();

  // phase C: out[r][e] = relu(sum_k h_s[r][k] * Wot[e][k]); 2 rows per thread
  const int rg = t >> 6;
  float acc2[2] = {0.f, 0.f};
  const float4* wo = (const float4*)(Wot + e * 512);
  for (int k4 = 0; k4 < 128; ++k4) {
    float4 w4 = wo[k4];
#pragma unroll
    for (int rr = 0; rr < 2; ++rr) {
      float4 x4 = ((const float4*)h_s)[(rg * 2 + rr) * 128 + k4];
      acc2[rr] = fmaf(w4.x, x4.x, acc2[rr]);
      acc2[rr] = fmaf(w4.y, x4.y, acc2[rr]);
      acc2[rr] = fmaf(w4.z, x4.z, acc2[rr]);
      acc2[rr] = fmaf(w4.w, x4.w, acc2[rr]);
    }
  }
#pragma unroll
  for (int rr = 0; rr < 2; ++rr) {
    float v = fmaxf(acc2[rr], 0.f);
    out[((size_t)(out_row_base + row0l + rg * 2 + rr)) * 64 + e] = v;  // f32 output
  }
}

extern "C" void kernel_launch(void* const* d_in, const int* in_sizes, int n_in,
                              void* d_out, int out_size, void* d_ws, size_t ws_size,
                              hipStream_t stream) {
  (void)in_sizes; (void)n_in; (void)out_size;
  const float* self_vecs  = (const float*)d_in[0];
  const float* neigh_vecs = (const float*)d_in[1];
  const float* W_heads    = (const float*)d_in[2];
  const float* a_self     = (const float*)d_in[3];
  const float* a_neigh    = (const float*)d_in[4];
  const float* W_out      = (const float*)d_in[5];
  float* out              = (float*)d_out;   // reference output dtype is FLOAT32

  char* ws = (char*)d_ws;
  const size_t PREP_BYTES = 4096 + 4096 + 262144 + 131072;  // 401,408
  float* w_neigh = (float*)ws;
  float* w_self  = (float*)(ws + 4096);
  float* Wt      = (float*)(ws + 8192);
  float* Wot     = (float*)(ws + 8192 + 262144);
  __hip_bfloat16* agg = (__hip_bfloat16*)(ws + PREP_BYTES);

  // Adapt chunk size to the actual workspace: agg needs G*H*DIN*2 = 8192 B per b.
  const long long per_b = (long long)GG * HH * DIN * 2;
  long long avail = (long long)ws_size - (long long)PREP_BYTES;
  long long c = avail / per_b;
  if (c > BB) c = BB;
  if (c < 2) c = 2;
  int chunk = (int)(c & ~1LL); // even, so rows per chunk divisible by 8

  prep_kernel<<<(2048 + 65536 + 32768) / 256, 256, 0, stream>>>(
      W_heads, a_self, a_neigh, W_out, w_neigh, w_self, Wt, Wot);

  for (int s = 0; s < BB; s += chunk) {
    int nb = BB - s < chunk ? BB - s : chunk;
    attn_agg_kernel<<<nb, 256, 0, stream>>>(self_vecs, neigh_vecs, w_neigh, w_self, agg, s);
    head_fc_kernel<<<nb * GG / 8, 256, 0, stream>>>(agg, Wt, Wot, out, s * GG);
  }
}

// Round 4
// 200.491 us; speedup vs baseline: 1.4580x; 1.4580x over previous
//
#include <hip/hip_runtime.h>
#include <hip/hip_bf16.h>

#define BB 4096
#define NNB 20
#define GG 4
#define DIN 128
#define EE 64
#define HH 8

__device__ __forceinline__ float lrelu_f(float x) { return x > 0.f ? x : 0.2f * x; }

// ---------------- K0: prep (fold a-vectors into per-head d-space vectors) ----------------
__global__ __launch_bounds__(256) void prep_kernel(
    const float* __restrict__ W_heads, const float* __restrict__ a_self,
    const float* __restrict__ a_neigh,
    float* __restrict__ w_neigh, float* __restrict__ w_self) {
  int id = blockIdx.x * 256 + threadIdx.x;
  if (id < 2048) {
    int sel = id >> 10;            // 0 -> neigh, 1 -> self
    int h = (id >> 7) & 7, d = id & 127;
    const float* a = sel ? a_self : a_neigh;
    const float* Wrow = W_heads + (h * DIN + d) * EE;
    float acc = 0.f;
    for (int e = 0; e < EE; ++e) acc = fmaf(Wrow[e], a[h * EE + e], acc);
    (sel ? w_self : w_neigh)[h * DIN + d] = acc;
  }
}

// ---------------- K1: per-b fused f + softmax + agg (no x staging; tiny LDS) ----------------
__global__ __launch_bounds__(256) void attn_agg_kernel(
    const float* __restrict__ self_vecs, const float* __restrict__ neigh_vecs,
    const float* __restrict__ w_neigh, const float* __restrict__ w_self,
    __hip_bfloat16* __restrict__ agg /* [chunk*G][H][DIN] bf16 */, int b0) {
  __shared__ float f_s[84][8];           // rows 0..79 neigh (n*4+g), 80..83 self g
  __shared__ float att_s[NNB * GG * HH]; // [n][g][h]

  const int bl = blockIdx.x;             // chunk-local b
  const int b = b0 + bl;                 // global b
  const int t = threadIdx.x;
  const float* nb = neigh_vecs + (size_t)b * (NNB * GG * DIN);

  // P1: f-dots. threads 0..167 -> (row, half). row<80: neigh row (n*4+g); 80..83: self row g.
  if (t < 168) {
    int row = t >> 1, q = t & 1;
    const float* xptr;
    const float* wptr;
    if (row < 80) { xptr = nb + row * DIN; wptr = w_neigh; }
    else          { xptr = self_vecs + ((size_t)b * GG + (row - 80)) * DIN; wptr = w_self; }
    float p[8] = {0.f, 0.f, 0.f, 0.f, 0.f, 0.f, 0.f, 0.f};
    const int base = q * 64;
    for (int j = 0; j < 16; ++j) {
      float4 x4 = *(const float4*)(xptr + base + 4 * j);
#pragma unroll
      for (int h = 0; h < 8; ++h) {
        float4 w4 = *(const float4*)(wptr + h * DIN + base + 4 * j);
        p[h] = fmaf(x4.x, w4.x, p[h]);
        p[h] = fmaf(x4.y, w4.y, p[h]);
        p[h] = fmaf(x4.z, w4.z, p[h]);
        p[h] = fmaf(x4.w, w4.w, p[h]);
      }
    }
#pragma unroll
    for (int h = 0; h < 8; ++h) p[h] += __shfl_xor(p[h], 1);
    if (q == 0) {
#pragma unroll
      for (int h = 0; h < 8; ++h) f_s[row][h] = p[h];
    }
  }
  __syncthreads();

  // P2: softmax over g for each (n,h). threads 0..159.
  if (t < 160) {
    int n = t >> 3, h = t & 7;
    float l[4], m = -1e30f;
#pragma unroll
    for (int g = 0; g < 4; ++g) {
      float v = lrelu_f(f_s[80 + g][h] + f_s[n * 4 + g][h]);
      l[g] = v;
      m = fmaxf(m, v);
    }
    float s = 0.f;
#pragma unroll
    for (int g = 0; g < 4; ++g) { l[g] = __expf(l[g] - m); s += l[g]; }
    float inv = 1.f / s;
#pragma unroll
    for (int g = 0; g < 4; ++g) att_s[(n * 4 + g) * 8 + h] = l[g] * inv;
  }
  __syncthreads();

  // P3: agg[g][h][d] = sum_n att[n][g][h] * x[n][g][d]; thread = (g, d-pair).
  // x re-read from global (L1/L2-hot after P1), coalesced float2 across lanes.
  {
    int g = t >> 6, d2 = t & 63;     // wave-uniform g
    float acc[8][2];
#pragma unroll
    for (int h = 0; h < 8; ++h) { acc[h][0] = 0.f; acc[h][1] = 0.f; }
    for (int n = 0; n < NNB; ++n) {
      float2 x2 = *(const float2*)&nb[(n * 4 + g) * DIN + d2 * 2];
#pragma unroll
      for (int h = 0; h < 8; ++h) {
        float a = att_s[(n * 4 + g) * 8 + h];
        acc[h][0] = fmaf(a, x2.x, acc[h][0]);
        acc[h][1] = fmaf(a, x2.y, acc[h][1]);
      }
    }
    __hip_bfloat16* ap = agg + ((size_t)(bl * GG + g) * HH) * DIN + d2 * 2;
#pragma unroll
    for (int h = 0; h < 8; ++h) {
      __hip_bfloat162 v2;
      v2.x = __float2bfloat16(acc[h][0]);
      v2.y = __float2bfloat16(acc[h][1]);
      *reinterpret_cast<__hip_bfloat162*>(ap + h * DIN) = v2;
    }
  }
}

// ---------------- K2: out_h matvec + final FC + relu, 8 rows per block ----------------
// Weights read in ORIGINAL layouts so lane (=e) is the contiguous axis (coalesced);
// activations broadcast from LDS (wave-uniform addresses, conflict-free).
__global__ __launch_bounds__(256) void head_fc_kernel(
    const __hip_bfloat16* __restrict__ agg, const float* __restrict__ W_heads,
    const float* __restrict__ W_out, float* __restrict__ out,
    int out_row_base /* = b0*G */) {
  __shared__ float agg_s[8 * 1024];  // 32 KB  [r][h*128+d] f32
  __shared__ float h_s[8 * 512];     // 16 KB  [r][k] f32

  const int t = threadIdx.x;
  const size_t row0l = (size_t)blockIdx.x * 8;   // chunk-local row

  // stage agg rows, bf16 -> f32 (coalesced)
  const unsigned int* au = (const unsigned int*)(agg + row0l * HH * DIN); // 4096 uints
  for (int k = 0; k < 16; ++k) {
    int idx = t + 256 * k;
    unsigned int u = au[idx];
    float lo = __uint_as_float(u << 16);
    float hi = __uint_as_float(u & 0xffff0000u);
    ((float2*)agg_s)[idx] = make_float2(lo, hi);
  }
  __syncthreads();

  const int e = t & 63;
  const int h0 = t >> 6;   // wave-uniform
  // phase B: out_h[r][hh*64+e] = lrelu(sum_d agg[r][hh][d] * W_heads[hh][d][e])
#pragma unroll
  for (int hi_ = 0; hi_ < 2; ++hi_) {
    int hh = h0 + 4 * hi_;
    float acc[8];
#pragma unroll
    for (int r = 0; r < 8; ++r) acc[r] = 0.f;
    const float* wp = W_heads + (size_t)hh * DIN * EE + e;   // stride EE per d
    for (int d4 = 0; d4 < 32; ++d4) {
      // 4 coalesced dword weight loads (lanes e consecutive)
      float w0 = wp[(d4 * 4 + 0) * EE];
      float w1 = wp[(d4 * 4 + 1) * EE];
      float w2 = wp[(d4 * 4 + 2) * EE];
      float w3 = wp[(d4 * 4 + 3) * EE];
#pragma unroll
      for (int r = 0; r < 8; ++r) {
        float4 x4 = ((const float4*)agg_s)[r * 256 + hh * 32 + d4];  // LDS broadcast
        acc[r] = fmaf(w0, x4.x, acc[r]);
        acc[r] = fmaf(w1, x4.y, acc[r]);
        acc[r] = fmaf(w2, x4.z, acc[r]);
        acc[r] = fmaf(w3, x4.w, acc[r]);
      }
    }
#pragma unroll
    for (int r = 0; r < 8; ++r) h_s[r * 512 + hh * 64 + e] = lrelu_f(acc[r]);
  }
  __syncthreads();

  // phase C: out[r][e] = relu(sum_k h_s[r][k] * W_out[k][e]); 2 rows per thread
  const int rg = t >> 6;
  float acc2[2] = {0.f, 0.f};
  for (int k4 = 0; k4 < 128; ++k4) {
    // 4 coalesced dword weight loads
    float w0 = W_out[(k4 * 4 + 0) * EE + e];
    float w1 = W_out[(k4 * 4 + 1) * EE + e];
    float w2 = W_out[(k4 * 4 + 2) * EE + e];
    float w3 = W_out[(k4 * 4 + 3) * EE + e];
#pragma unroll
    for (int rr = 0; rr < 2; ++rr) {
      float4 x4 = ((const float4*)h_s)[(rg * 2 + rr) * 128 + k4];   // LDS broadcast
      acc2[rr] = fmaf(w0, x4.x, acc2[rr]);
      acc2[rr] = fmaf(w1, x4.y, acc2[rr]);
      acc2[rr] = fmaf(w2, x4.z, acc2[rr]);
      acc2[rr] = fmaf(w3, x4.w, acc2[rr]);
    }
  }
#pragma unroll
  for (int rr = 0; rr < 2; ++rr) {
    float v = fmaxf(acc2[rr], 0.f);
    out[((size_t)(out_row_base + row0l + rg * 2 + rr)) * 64 + e] = v;  // f32 output
  }
}

extern "C" void kernel_launch(void* const* d_in, const int* in_sizes, int n_in,
                              void* d_out, int out_size, void* d_ws, size_t ws_size,
                              hipStream_t stream) {
  (void)in_sizes; (void)n_in; (void)out_size;
  const float* self_vecs  = (const float*)d_in[0];
  const float* neigh_vecs = (const float*)d_in[1];
  const float* W_heads    = (const float*)d_in[2];
  const float* a_self     = (const float*)d_in[3];
  const float* a_neigh    = (const float*)d_in[4];
  const float* W_out      = (const float*)d_in[5];
  float* out              = (float*)d_out;

  char* ws = (char*)d_ws;
  const size_t PREP_BYTES = 4096 + 4096;  // w_neigh + w_self
  float* w_neigh = (float*)ws;
  float* w_self  = (float*)(ws + 4096);
  __hip_bfloat16* agg = (__hip_bfloat16*)(ws + PREP_BYTES);

  // Adapt chunk size to the actual workspace: agg needs G*H*DIN*2 = 8192 B per b.
  const long long per_b = (long long)GG * HH * DIN * 2;
  long long avail = (long long)ws_size - (long long)PREP_BYTES;
  long long c = avail / per_b;
  if (c > BB) c = BB;
  if (c < 2) c = 2;
  int chunk = (int)(c & ~1LL); // even, so rows per chunk divisible by 8

  prep_kernel<<<8, 256, 0, stream>>>(W_heads, a_self, a_neigh, w_neigh, w_self);

  for (int s = 0; s < BB; s += chunk) {
    int nb = BB - s < chunk ? BB - s : chunk;
    attn_agg_kernel<<<nb, 256, 0, stream>>>(self_vecs, neigh_vecs, w_neigh, w_self, agg, s);
    head_fc_kernel<<<nb * GG / 8, 256, 0, stream>>>(agg, W_heads, W_out, out, s * GG);
  }
}

// Round 5
// 161.670 us; speedup vs baseline: 1.8081x; 1.2401x over previous
//
#include <hip/hip_runtime.h>
#include <hip/hip_bf16.h>

#define BB 4096
#define NNB 20
#define GG 4
#define DIN 128
#define EE 64
#define HH 8

__device__ __forceinline__ float lrelu_f(float x) { return x > 0.f ? x : 0.2f * x; }

// ---------------- K0: prep (fold a-vectors into per-head d-space vectors) ----------------
__global__ __launch_bounds__(256) void prep_kernel(
    const float* __restrict__ W_heads, const float* __restrict__ a_self,
    const float* __restrict__ a_neigh,
    float* __restrict__ w_neigh, float* __restrict__ w_self) {
  int id = blockIdx.x * 256 + threadIdx.x;
  if (id < 2048) {
    int sel = id >> 10;            // 0 -> neigh, 1 -> self
    int h = (id >> 7) & 7, d = id & 127;
    const float* a = sel ? a_self : a_neigh;
    const float* Wrow = W_heads + (h * DIN + d) * EE;
    float acc = 0.f;
    for (int e = 0; e < EE; ++e) acc = fmaf(Wrow[e], a[h * EE + e], acc);
    (sel ? w_self : w_neigh)[h * DIN + d] = acc;
  }
}

// h-split butterfly: input acc[h] = per-lane partial for all 8 h.
// Output: full 64-lane sum for h(lane) = ((lane&1)<<2) | (lane&2) | ((lane>>2)&1).
__device__ __forceinline__ float hreduce8(const float a[8], int lane) {
  float b[4];
#pragma unroll
  for (int i = 0; i < 4; ++i) {
    float lo = a[i]     + __shfl_xor(a[i],     1);
    float hi = a[i + 4] + __shfl_xor(a[i + 4], 1);
    b[i] = (lane & 1) ? hi : lo;
  }
  float c[2];
#pragma unroll
  for (int i = 0; i < 2; ++i) {
    float lo = b[i]     + __shfl_xor(b[i],     2);
    float hi = b[i + 2] + __shfl_xor(b[i + 2], 2);
    c[i] = (lane & 2) ? hi : lo;
  }
  float lo = c[0] + __shfl_xor(c[0], 4);
  float hi = c[1] + __shfl_xor(c[1], 4);
  float d = (lane & 4) ? hi : lo;
  d += __shfl_xor(d, 8);
  d += __shfl_xor(d, 16);
  d += __shfl_xor(d, 32);
  return d;
}

// ---------------- K1: per-b fused f + softmax + agg (lane=d, x in regs, coalesced) ----------------
__global__ __launch_bounds__(256) void attn_agg_kernel(
    const float* __restrict__ self_vecs, const float* __restrict__ neigh_vecs,
    const float* __restrict__ w_neigh, const float* __restrict__ w_self,
    __hip_bfloat16* __restrict__ agg /* [chunk*G][H][DIN] bf16 */, int b0) {
  __shared__ float f_s[84][8];           // rows 0..79 neigh (n*4+g), 80..83 self g
  __shared__ float att_s[NNB * GG * HH]; // [n][g][h]

  const int bl = blockIdx.x;
  const int b = b0 + bl;
  const int t = threadIdx.x;
  const int g = t >> 6;          // wave id = graph id (wave-uniform)
  const int lane = t & 63;
  const float* nb = neigh_vecs + (size_t)b * (NNB * GG * DIN);

  // Preload weights to regs (coalesced float2 per lane).
  float2 wn2[8], ws2[8];
#pragma unroll
  for (int h = 0; h < 8; ++h) {
    wn2[h] = *(const float2*)&w_neigh[h * DIN + 2 * lane];
    ws2[h] = *(const float2*)&w_self [h * DIN + 2 * lane];
  }
  // Load this wave's 20 neigh rows + self row, coalesced, ONCE (kept in regs for P3).
  float2 xr[NNB];
#pragma unroll
  for (int n = 0; n < NNB; ++n)
    xr[n] = *(const float2*)&nb[(n * GG + g) * DIN + 2 * lane];
  float2 xs = *(const float2*)&self_vecs[((size_t)b * GG + g) * DIN + 2 * lane];

  const int hm = ((lane & 1) << 2) | (lane & 2) | ((lane >> 2) & 1);

  // P1: f-dots via butterfly reduce; 8 lanes write f_s[row][h].
#pragma unroll
  for (int n = 0; n < NNB; ++n) {
    float acc[8];
#pragma unroll
    for (int h = 0; h < 8; ++h)
      acc[h] = xr[n].x * wn2[h].x + xr[n].y * wn2[h].y;
    float f = hreduce8(acc, lane);
    if (lane < 8) f_s[n * GG + g][hm] = f;
  }
  {
    float acc[8];
#pragma unroll
    for (int h = 0; h < 8; ++h)
      acc[h] = xs.x * ws2[h].x + xs.y * ws2[h].y;
    float f = hreduce8(acc, lane);
    if (lane < 8) f_s[80 + g][hm] = f;
  }
  __syncthreads();

  // P2: softmax over g for each (n,h). threads 0..159.
  if (t < 160) {
    int n = t >> 3, h = t & 7;
    float l[4], m = -1e30f;
#pragma unroll
    for (int gg = 0; gg < 4; ++gg) {
      float v = lrelu_f(f_s[80 + gg][h] + f_s[n * 4 + gg][h]);
      l[gg] = v;
      m = fmaxf(m, v);
    }
    float s = 0.f;
#pragma unroll
    for (int gg = 0; gg < 4; ++gg) { l[gg] = __expf(l[gg] - m); s += l[gg]; }
    float inv = 1.f / s;
#pragma unroll
    for (int gg = 0; gg < 4; ++gg) att_s[(n * 4 + gg) * 8 + h] = l[gg] * inv;
  }
  __syncthreads();

  // P3: agg[g][h][d] = sum_n att[n][g][h] * x[n][g][d]; x already in regs.
  {
    float acc[8][2];
#pragma unroll
    for (int h = 0; h < 8; ++h) { acc[h][0] = 0.f; acc[h][1] = 0.f; }
#pragma unroll
    for (int n = 0; n < NNB; ++n) {
      const float* at = &att_s[(n * GG + g) * 8];   // wave-uniform -> LDS broadcast
#pragma unroll
      for (int h = 0; h < 8; ++h) {
        float a = at[h];
        acc[h][0] = fmaf(a, xr[n].x, acc[h][0]);
        acc[h][1] = fmaf(a, xr[n].y, acc[h][1]);
      }
    }
    __hip_bfloat16* ap = agg + ((size_t)(bl * GG + g) * HH) * DIN + 2 * lane;
#pragma unroll
    for (int h = 0; h < 8; ++h) {
      __hip_bfloat162 v2;
      v2.x = __float2bfloat16(acc[h][0]);
      v2.y = __float2bfloat16(acc[h][1]);
      *reinterpret_cast<__hip_bfloat162*>(ap + h * DIN) = v2;
    }
  }
}

// ---------------- K2: out_h matvec + final FC + relu, 8 rows per block (unchanged) ----------------
__global__ __launch_bounds__(256) void head_fc_kernel(
    const __hip_bfloat16* __restrict__ agg, const float* __restrict__ W_heads,
    const float* __restrict__ W_out, float* __restrict__ out,
    int out_row_base /* = b0*G */) {
  __shared__ float agg_s[8 * 1024];  // 32 KB  [r][h*128+d] f32
  __shared__ float h_s[8 * 512];     // 16 KB  [r][k] f32

  const int t = threadIdx.x;
  const size_t row0l = (size_t)blockIdx.x * 8;

  const unsigned int* au = (const unsigned int*)(agg + row0l * HH * DIN); // 4096 uints
  for (int k = 0; k < 16; ++k) {
    int idx = t + 256 * k;
    unsigned int u = au[idx];
    float lo = __uint_as_float(u << 16);
    float hi = __uint_as_float(u & 0xffff0000u);
    ((float2*)agg_s)[idx] = make_float2(lo, hi);
  }
  __syncthreads();

  const int e = t & 63;
  const int h0 = t >> 6;
#pragma unroll
  for (int hi_ = 0; hi_ < 2; ++hi_) {
    int hh = h0 + 4 * hi_;
    float acc[8];
#pragma unroll
    for (int r = 0; r < 8; ++r) acc[r] = 0.f;
    const float* wp = W_heads + (size_t)hh * DIN * EE + e;   // stride EE per d
    for (int d4 = 0; d4 < 32; ++d4) {
      float w0 = wp[(d4 * 4 + 0) * EE];
      float w1 = wp[(d4 * 4 + 1) * EE];
      float w2 = wp[(d4 * 4 + 2) * EE];
      float w3 = wp[(d4 * 4 + 3) * EE];
#pragma unroll
      for (int r = 0; r < 8; ++r) {
        float4 x4 = ((const float4*)agg_s)[r * 256 + hh * 32 + d4];
        acc[r] = fmaf(w0, x4.x, acc[r]);
        acc[r] = fmaf(w1, x4.y, acc[r]);
        acc[r] = fmaf(w2, x4.z, acc[r]);
        acc[r] = fmaf(w3, x4.w, acc[r]);
      }
    }
#pragma unroll
    for (int r = 0; r < 8; ++r) h_s[r * 512 + hh * 64 + e] = lrelu_f(acc[r]);
  }
  __syncthreads();

  const int rg = t >> 6;
  float acc2[2] = {0.f, 0.f};
  for (int k4 = 0; k4 < 128; ++k4) {
    float w0 = W_out[(k4 * 4 + 0) * EE + e];
    float w1 = W_out[(k4 * 4 + 1) * EE + e];
    float w2 = W_out[(k4 * 4 + 2) * EE + e];
    float w3 = W_out[(k4 * 4 + 3) * EE + e];
#pragma unroll
    for (int rr = 0; rr < 2; ++rr) {
      float4 x4 = ((const float4*)h_s)[(rg * 2 + rr) * 128 + k4];
      acc2[rr] = fmaf(w0, x4.x, acc2[rr]);
      acc2[rr] = fmaf(w1, x4.y, acc2[rr]);
      acc2[rr] = fmaf(w2, x4.z, acc2[rr]);
      acc2[rr] = fmaf(w3, x4.w, acc2[rr]);
    }
  }
#pragma unroll
  for (int rr = 0; rr < 2; ++rr) {
    float v = fmaxf(acc2[rr], 0.f);
    out[((size_t)(out_row_base + row0l + rg * 2 + rr)) * 64 + e] = v;
  }
}

extern "C" void kernel_launch(void* const* d_in, const int* in_sizes, int n_in,
                              void* d_out, int out_size, void* d_ws, size_t ws_size,
                              hipStream_t stream) {
  (void)in_sizes; (void)n_in; (void)out_size;
  const float* self_vecs  = (const float*)d_in[0];
  const float* neigh_vecs = (const float*)d_in[1];
  const float* W_heads    = (const float*)d_in[2];
  const float* a_self     = (const float*)d_in[3];
  const float* a_neigh    = (const float*)d_in[4];
  const float* W_out      = (const float*)d_in[5];
  float* out              = (float*)d_out;

  char* ws = (char*)d_ws;
  const size_t PREP_BYTES = 4096 + 4096;  // w_neigh + w_self
  float* w_neigh = (float*)ws;
  float* w_self  = (float*)(ws + 4096);
  __hip_bfloat16* agg = (__hip_bfloat16*)(ws + PREP_BYTES);

  const long long per_b = (long long)GG * HH * DIN * 2;  // 8192 B per b
  long long avail = (long long)ws_size - (long long)PREP_BYTES;
  long long c = avail / per_b;
  if (c > BB) c = BB;
  if (c < 2) c = 2;
  int chunk = (int)(c & ~1LL);

  prep_kernel<<<8, 256, 0, stream>>>(W_heads, a_self, a_neigh, w_neigh, w_self);

  for (int s = 0; s < BB; s += chunk) {
    int nb = BB - s < chunk ? BB - s : chunk;
    attn_agg_kernel<<<nb, 256, 0, stream>>>(self_vecs, neigh_vecs, w_neigh, w_self, agg, s);
    head_fc_kernel<<<nb * GG / 8, 256, 0, stream>>>(agg, W_heads, W_out, out, s * GG);
  }
}

// Round 6
// 121.794 us; speedup vs baseline: 2.4001x; 1.3274x over previous
//
#include <hip/hip_runtime.h>
#include <hip/hip_bf16.h>

#define BB 4096
#define NNB 20
#define GG 4
#define DIN 128
#define EE 64
#define HH 8

typedef short bf16x8 __attribute__((ext_vector_type(8)));
typedef float f32x4 __attribute__((ext_vector_type(4)));

__device__ __forceinline__ float lrelu_f(float x) { return x > 0.f ? x : 0.2f * x; }
__device__ __forceinline__ unsigned short f2bf(float f) {
  unsigned u = __float_as_uint(f);
  return (unsigned short)((u + 0x7fffu + ((u >> 16) & 1u)) >> 16);
}
__device__ __forceinline__ float bf2f(unsigned short s) {
  return __uint_as_float(((unsigned)s) << 16);
}

// ---------------- K0: prep ----------------
// [0,2048): folded a-vectors. [2048,2048+65536): WB hi/lo frag-packed.
// [.., +32768): WO hi/lo frag-packed.
__global__ __launch_bounds__(256) void prep_kernel(
    const float* __restrict__ W_heads, const float* __restrict__ a_self,
    const float* __restrict__ a_neigh, const float* __restrict__ W_out,
    float* __restrict__ w_neigh, float* __restrict__ w_self,
    unsigned short* __restrict__ WBhi, unsigned short* __restrict__ WBlo,
    unsigned short* __restrict__ WOhi, unsigned short* __restrict__ WOlo) {
  int id = blockIdx.x * 256 + threadIdx.x;
  if (id < 2048) {
    int sel = id >> 10;            // 0 -> neigh, 1 -> self
    int h = (id >> 7) & 7, d = id & 127;
    const float* a = sel ? a_self : a_neigh;
    const float* Wrow = W_heads + (h * DIN + d) * EE;
    float acc = 0.f;
    for (int e = 0; e < EE; ++e) acc = fmaf(Wrow[e], a[h * EE + e], acc);
    (sel ? w_self : w_neigh)[h * DIN + d] = acc;
  } else if (id < 2048 + 65536) {
    // WB frag element: rel = (((h*4+nt)*4+kb)*64 + l)*8 + j
    int rel = id - 2048;
    int j = rel & 7, l = (rel >> 3) & 63, kb = (rel >> 9) & 3, nt = (rel >> 11) & 3, h = rel >> 13;
    int d = kb * 32 + (l >> 4) * 8 + j;
    int e = nt * 16 + (l & 15);
    float w = W_heads[(h * DIN + d) * EE + e];
    unsigned short hi = f2bf(w);
    unsigned short lo = f2bf(w - bf2f(hi));
    WBhi[rel] = hi; WBlo[rel] = lo;
  } else if (id < 2048 + 65536 + 32768) {
    // WO frag element: rel = ((nt*16+kb)*64 + l)*8 + j
    int rel = id - 2048 - 65536;
    int j = rel & 7, l = (rel >> 3) & 63, kb = (rel >> 9) & 15, nt = rel >> 13;
    int k = kb * 32 + (l >> 4) * 8 + j;
    int n = nt * 16 + (l & 15);
    float w = W_out[k * EE + n];
    unsigned short hi = f2bf(w);
    unsigned short lo = f2bf(w - bf2f(hi));
    WOhi[rel] = hi; WOlo[rel] = lo;
  }
}

// h-split butterfly: input acc[h] = per-lane partial for all 8 h.
// Output: full 64-lane sum for h(lane) = ((lane&1)<<2) | (lane&2) | ((lane>>2)&1).
__device__ __forceinline__ float hreduce8(const float a[8], int lane) {
  float b[4];
#pragma unroll
  for (int i = 0; i < 4; ++i) {
    float lo = a[i]     + __shfl_xor(a[i],     1);
    float hi = a[i + 4] + __shfl_xor(a[i + 4], 1);
    b[i] = (lane & 1) ? hi : lo;
  }
  float c[2];
#pragma unroll
  for (int i = 0; i < 2; ++i) {
    float lo = b[i]     + __shfl_xor(b[i],     2);
    float hi = b[i + 2] + __shfl_xor(b[i + 2], 2);
    c[i] = (lane & 2) ? hi : lo;
  }
  float lo = c[0] + __shfl_xor(c[0], 4);
  float hi = c[1] + __shfl_xor(c[1], 4);
  float d = (lane & 4) ? hi : lo;
  d += __shfl_xor(d, 8);
  d += __shfl_xor(d, 16);
  d += __shfl_xor(d, 32);
  return d;
}

// ---------------- K1: per-b fused f + softmax + agg (unchanged from R5) ----------------
__global__ __launch_bounds__(256) void attn_agg_kernel(
    const float* __restrict__ self_vecs, const float* __restrict__ neigh_vecs,
    const float* __restrict__ w_neigh, const float* __restrict__ w_self,
    __hip_bfloat16* __restrict__ agg /* [chunk*G][H][DIN] bf16 */, int b0) {
  __shared__ float f_s[84][8];
  __shared__ float att_s[NNB * GG * HH];

  const int bl = blockIdx.x;
  const int b = b0 + bl;
  const int t = threadIdx.x;
  const int g = t >> 6;
  const int lane = t & 63;
  const float* nb = neigh_vecs + (size_t)b * (NNB * GG * DIN);

  float2 wn2[8], ws2[8];
#pragma unroll
  for (int h = 0; h < 8; ++h) {
    wn2[h] = *(const float2*)&w_neigh[h * DIN + 2 * lane];
    ws2[h] = *(const float2*)&w_self [h * DIN + 2 * lane];
  }
  float2 xr[NNB];
#pragma unroll
  for (int n = 0; n < NNB; ++n)
    xr[n] = *(const float2*)&nb[(n * GG + g) * DIN + 2 * lane];
  float2 xs = *(const float2*)&self_vecs[((size_t)b * GG + g) * DIN + 2 * lane];

  const int hm = ((lane & 1) << 2) | (lane & 2) | ((lane >> 2) & 1);

#pragma unroll
  for (int n = 0; n < NNB; ++n) {
    float acc[8];
#pragma unroll
    for (int h = 0; h < 8; ++h)
      acc[h] = xr[n].x * wn2[h].x + xr[n].y * wn2[h].y;
    float f = hreduce8(acc, lane);
    if (lane < 8) f_s[n * GG + g][hm] = f;
  }
  {
    float acc[8];
#pragma unroll
    for (int h = 0; h < 8; ++h)
      acc[h] = xs.x * ws2[h].x + xs.y * ws2[h].y;
    float f = hreduce8(acc, lane);
    if (lane < 8) f_s[80 + g][hm] = f;
  }
  __syncthreads();

  if (t < 160) {
    int n = t >> 3, h = t & 7;
    float l[4], m = -1e30f;
#pragma unroll
    for (int gg = 0; gg < 4; ++gg) {
      float v = lrelu_f(f_s[80 + gg][h] + f_s[n * 4 + gg][h]);
      l[gg] = v;
      m = fmaxf(m, v);
    }
    float s = 0.f;
#pragma unroll
    for (int gg = 0; gg < 4; ++gg) { l[gg] = __expf(l[gg] - m); s += l[gg]; }
    float inv = 1.f / s;
#pragma unroll
    for (int gg = 0; gg < 4; ++gg) att_s[(n * 4 + gg) * 8 + h] = l[gg] * inv;
  }
  __syncthreads();

  {
    float acc[8][2];
#pragma unroll
    for (int h = 0; h < 8; ++h) { acc[h][0] = 0.f; acc[h][1] = 0.f; }
#pragma unroll
    for (int n = 0; n < NNB; ++n) {
      const float* at = &att_s[(n * GG + g) * 8];
#pragma unroll
      for (int h = 0; h < 8; ++h) {
        float a = at[h];
        acc[h][0] = fmaf(a, xr[n].x, acc[h][0]);
        acc[h][1] = fmaf(a, xr[n].y, acc[h][1]);
      }
    }
    __hip_bfloat16* ap = agg + ((size_t)(bl * GG + g) * HH) * DIN + 2 * lane;
#pragma unroll
    for (int h = 0; h < 8; ++h) {
      __hip_bfloat162 v2;
      v2.x = __float2bfloat16(acc[h][0]);
      v2.y = __float2bfloat16(acc[h][1]);
      *reinterpret_cast<__hip_bfloat162*>(ap + h * DIN) = v2;
    }
  }
}

// ---------------- K2: MFMA head transform + final FC ----------------
// Block = 64 rows, 4 waves; wave w owns rows [blk*64+w*16, +16).
// Phase B per head: C1[16x64] = agg[16x128] x Wh[128x64] via 16x16x32 bf16 MFMA,
//   weights split hi/lo (2 MFMA). lrelu -> f32 LDS tile [16][512], XOR-swizzled.
// Phase C: out[16x64] = h[16x512] x W_out[512x64], h split hi/lo (3-product).
__global__ __launch_bounds__(256) void head_fc_mfma(
    const __hip_bfloat16* __restrict__ agg,
    const unsigned short* __restrict__ WBhi, const unsigned short* __restrict__ WBlo,
    const unsigned short* __restrict__ WOhi, const unsigned short* __restrict__ WOlo,
    float* __restrict__ out, int out_row_base) {
  __shared__ float hlds[4 * 16 * 512];  // 128 KB, per-wave-private 32 KB tiles

  const int t = threadIdx.x;
  const int wave = t >> 6, lane = t & 63;
  const int m = lane & 15, kg = lane >> 4;
  const int r0w = blockIdx.x * 64 + wave * 16;   // chunk-local row base for this wave
  char* wbase = (char*)&hlds[wave * 16 * 512];

  // ---- phase B ----
  for (int h = 0; h < 8; ++h) {
    bf16x8 a[4];
#pragma unroll
    for (int kb = 0; kb < 4; ++kb)
      a[kb] = *(const bf16x8*)(agg + (size_t)(r0w + m) * (HH * DIN) + h * DIN + kb * 32 + kg * 8);
#pragma unroll
    for (int nt = 0; nt < 4; ++nt) {
      f32x4 c = {0.f, 0.f, 0.f, 0.f};
#pragma unroll
      for (int kb = 0; kb < 4; ++kb) {
        const int fi = (((h * 4 + nt) * 4 + kb) * 64 + lane) * 8;
        bf16x8 bh = *(const bf16x8*)(WBhi + fi);
        bf16x8 bl = *(const bf16x8*)(WBlo + fi);
        c = __builtin_amdgcn_mfma_f32_16x16x32_bf16(a[kb], bh, c, 0, 0, 0);
        c = __builtin_amdgcn_mfma_f32_16x16x32_bf16(a[kb], bl, c, 0, 0, 0);
      }
      // D layout: col = lane&15 (=e within tile), row = kg*4+reg
      const int k = h * 64 + nt * 16 + m;  // phase-C k index
#pragma unroll
      for (int reg = 0; reg < 4; ++reg) {
        int lr = kg * 4 + reg;
        int byte = (lr * 2048 + k * 4) ^ ((lr & 7) << 4);
        *(float*)(wbase + byte) = lrelu_f(c[reg]);
      }
    }
  }

  // ---- phase C ---- (reads only this wave's private LDS tile; no barrier needed)
  f32x4 acc[4];
#pragma unroll
  for (int nt = 0; nt < 4; ++nt) acc[nt] = (f32x4){0.f, 0.f, 0.f, 0.f};

  for (int kb = 0; kb < 16; ++kb) {
    const int swz = (m & 7) << 4;
    const int b0 = m * 2048 + (kb * 32 + kg * 8) * 4;
    float4 f0 = *(const float4*)(wbase + ((b0)      ^ swz));
    float4 f1 = *(const float4*)(wbase + ((b0 + 16) ^ swz));
    float fv[8] = {f0.x, f0.y, f0.z, f0.w, f1.x, f1.y, f1.z, f1.w};
    bf16x8 ahi, alo;
#pragma unroll
    for (int j = 0; j < 8; ++j) {
      unsigned short hi = f2bf(fv[j]);
      unsigned short lo = f2bf(fv[j] - bf2f(hi));
      ahi[j] = (short)hi;
      alo[j] = (short)lo;
    }
#pragma unroll
    for (int nt = 0; nt < 4; ++nt) {
      const int fi = ((nt * 16 + kb) * 64 + lane) * 8;
      bf16x8 bh = *(const bf16x8*)(WOhi + fi);
      bf16x8 bl = *(const bf16x8*)(WOlo + fi);
      acc[nt] = __builtin_amdgcn_mfma_f32_16x16x32_bf16(ahi, bh, acc[nt], 0, 0, 0);
      acc[nt] = __builtin_amdgcn_mfma_f32_16x16x32_bf16(ahi, bl, acc[nt], 0, 0, 0);
      acc[nt] = __builtin_amdgcn_mfma_f32_16x16x32_bf16(alo, bh, acc[nt], 0, 0, 0);
    }
  }

  const int rbase = out_row_base + r0w;
#pragma unroll
  for (int nt = 0; nt < 4; ++nt)
#pragma unroll
    for (int reg = 0; reg < 4; ++reg) {
      int row = rbase + kg * 4 + reg;
      out[(size_t)row * EE + nt * 16 + m] = fmaxf(acc[nt][reg], 0.f);
    }
}

extern "C" void kernel_launch(void* const* d_in, const int* in_sizes, int n_in,
                              void* d_out, int out_size, void* d_ws, size_t ws_size,
                              hipStream_t stream) {
  (void)in_sizes; (void)n_in; (void)out_size;
  const float* self_vecs  = (const float*)d_in[0];
  const float* neigh_vecs = (const float*)d_in[1];
  const float* W_heads    = (const float*)d_in[2];
  const float* a_self     = (const float*)d_in[3];
  const float* a_neigh    = (const float*)d_in[4];
  const float* W_out      = (const float*)d_in[5];
  float* out              = (float*)d_out;

  char* ws = (char*)d_ws;
  float* w_neigh = (float*)ws;                               // 4 KB
  float* w_self  = (float*)(ws + 4096);                      // 4 KB
  unsigned short* WBhi = (unsigned short*)(ws + 8192);       // 128 KB
  unsigned short* WBlo = (unsigned short*)(ws + 8192 + 131072);
  unsigned short* WOhi = (unsigned short*)(ws + 8192 + 262144);   // 64 KB
  unsigned short* WOlo = (unsigned short*)(ws + 8192 + 262144 + 65536);
  const size_t PREP_BYTES = 8192 + 262144 + 131072;          // 401,408
  __hip_bfloat16* agg = (__hip_bfloat16*)(ws + PREP_BYTES);

  // agg needs G*H*DIN*2 = 8192 B per b; chunk must be a multiple of 16
  // (rows per chunk divisible by 64 for head_fc_mfma).
  const long long per_b = (long long)GG * HH * DIN * 2;
  long long avail = (long long)ws_size - (long long)PREP_BYTES;
  long long c = avail / per_b;
  if (c > BB) c = BB;
  if (c < 16) c = 16;
  int chunk = (int)(c & ~15LL);

  prep_kernel<<<(2048 + 65536 + 32768 + 255) / 256, 256, 0, stream>>>(
      W_heads, a_self, a_neigh, W_out, w_neigh, w_self, WBhi, WBlo, WOhi, WOlo);

  for (int s = 0; s < BB; s += chunk) {
    int nb = BB - s < chunk ? BB - s : chunk;   // multiple of 16 (4096 = 16*256)
    attn_agg_kernel<<<nb, 256, 0, stream>>>(self_vecs, neigh_vecs, w_neigh, w_self, agg, s);
    head_fc_mfma<<<nb / 16, 256, 0, stream>>>(agg, WBhi, WBlo, WOhi, WOlo, out, s * GG);
  }
}

// Round 7
// 110.297 us; speedup vs baseline: 2.6503x; 1.1042x over previous
//
#include <hip/hip_runtime.h>
#include <hip/hip_bf16.h>

#define BB 4096
#define NNB 20
#define GG 4
#define DIN 128
#define EE 64
#define HH 8

typedef short bf16x8 __attribute__((ext_vector_type(8)));
typedef float f32x4 __attribute__((ext_vector_type(4)));

__device__ __forceinline__ float lrelu_f(float x) { return x > 0.f ? x : 0.2f * x; }
__device__ __forceinline__ unsigned short f2bf(float f) {
  unsigned u = __float_as_uint(f);
  return (unsigned short)((u + 0x7fffu + ((u >> 16) & 1u)) >> 16);
}
__device__ __forceinline__ float bf2f(unsigned short s) {
  return __uint_as_float(((unsigned)s) << 16);
}

// ---------------- K0: prep (unchanged from R6) ----------------
__global__ __launch_bounds__(256) void prep_kernel(
    const float* __restrict__ W_heads, const float* __restrict__ a_self,
    const float* __restrict__ a_neigh, const float* __restrict__ W_out,
    float* __restrict__ w_neigh, float* __restrict__ w_self,
    unsigned short* __restrict__ WBhi, unsigned short* __restrict__ WBlo,
    unsigned short* __restrict__ WOhi, unsigned short* __restrict__ WOlo) {
  int id = blockIdx.x * 256 + threadIdx.x;
  if (id < 2048) {
    int sel = id >> 10;
    int h = (id >> 7) & 7, d = id & 127;
    const float* a = sel ? a_self : a_neigh;
    const float* Wrow = W_heads + (h * DIN + d) * EE;
    float acc = 0.f;
    for (int e = 0; e < EE; ++e) acc = fmaf(Wrow[e], a[h * EE + e], acc);
    (sel ? w_self : w_neigh)[h * DIN + d] = acc;
  } else if (id < 2048 + 65536) {
    int rel = id - 2048;   // (((h*4+nt)*4+kb)*64 + l)*8 + j
    int j = rel & 7, l = (rel >> 3) & 63, kb = (rel >> 9) & 3, nt = (rel >> 11) & 3, h = rel >> 13;
    int d = kb * 32 + (l >> 4) * 8 + j;
    int e = nt * 16 + (l & 15);
    float w = W_heads[(h * DIN + d) * EE + e];
    unsigned short hi = f2bf(w);
    unsigned short lo = f2bf(w - bf2f(hi));
    WBhi[rel] = hi; WBlo[rel] = lo;
  } else if (id < 2048 + 65536 + 32768) {
    int rel = id - 2048 - 65536;  // ((nt*16+kb)*64 + l)*8 + j
    int j = rel & 7, l = (rel >> 3) & 63, kb = (rel >> 9) & 15, nt = rel >> 13;
    int k = kb * 32 + (l >> 4) * 8 + j;
    int n = nt * 16 + (l & 15);
    float w = W_out[k * EE + n];
    unsigned short hi = f2bf(w);
    unsigned short lo = f2bf(w - bf2f(hi));
    WOhi[rel] = hi; WOlo[rel] = lo;
  }
}

// h-split butterfly (unchanged). Output lane holds full sum for
// h(lane) = ((lane&1)<<2) | (lane&2) | ((lane>>2)&1).
__device__ __forceinline__ float hreduce8(const float a[8], int lane) {
  float b[4];
#pragma unroll
  for (int i = 0; i < 4; ++i) {
    float lo = a[i]     + __shfl_xor(a[i],     1);
    float hi = a[i + 4] + __shfl_xor(a[i + 4], 1);
    b[i] = (lane & 1) ? hi : lo;
  }
  float c[2];
#pragma unroll
  for (int i = 0; i < 2; ++i) {
    float lo = b[i]     + __shfl_xor(b[i],     2);
    float hi = b[i + 2] + __shfl_xor(b[i + 2], 2);
    c[i] = (lane & 2) ? hi : lo;
  }
  float lo = c[0] + __shfl_xor(c[0], 4);
  float hi = c[1] + __shfl_xor(c[1], 4);
  float d = (lane & 4) ? hi : lo;
  d += __shfl_xor(d, 8);
  d += __shfl_xor(d, 16);
  d += __shfl_xor(d, 32);
  return d;
}

// ---------------- Fused kernel: block = 4 b's = one 16-row (b,g) tile ----------------
// LDS (64 KB):
//   [0,32768):      agg tile, bf16 [row16][h*128+d], byte ^ ((row&7)<<4)
//   [32768,65536):  attn phase: f_s [4][84][8] f32 (10752 B) + att_s [4][640] f32 (10240 B)
//                   mfma phase: h_lds [16][512] f32, byte ^ ((row&7)<<4)
__global__ __launch_bounds__(256) void fused_kernel(
    const float* __restrict__ self_vecs, const float* __restrict__ neigh_vecs,
    const float* __restrict__ w_neigh, const float* __restrict__ w_self,
    const unsigned short* __restrict__ WBhi, const unsigned short* __restrict__ WBlo,
    const unsigned short* __restrict__ WOhi, const unsigned short* __restrict__ WOlo,
    float* __restrict__ out) {
  __shared__ char smem[65536];
  char* aggb = smem;                       // 32 KB agg tile (bytes)
  float* f_s   = (float*)(smem + 32768);   // [bl*84 + row][h]
  float* att_s = (float*)(smem + 32768 + 10752);  // [bl*640 + idx]
  char* hb = smem + 32768;                 // h_lds (bytes), reused after attn

  const int t = threadIdx.x;
  const int w = t >> 6;                    // wave id = graph g (attn), h-pair / nt (mfma)
  const int lane = t & 63;
  const int bid = blockIdx.x;

  // preload folded weight vectors (coalesced float2/lane)
  float2 wn2[8], ws2[8];
#pragma unroll
  for (int h = 0; h < 8; ++h) {
    wn2[h] = *(const float2*)&w_neigh[h * DIN + 2 * lane];
    ws2[h] = *(const float2*)&w_self [h * DIN + 2 * lane];
  }
  const int hm = ((lane & 1) << 2) | (lane & 2) | ((lane >> 2) & 1);

  // ======== attn phase: 4 b's sequentially ========
  for (int bl = 0; bl < 4; ++bl) {
    const int b = bid * 4 + bl;
    const float* nb = neigh_vecs + (size_t)b * (NNB * GG * DIN);

    float2 xr[NNB];
#pragma unroll
    for (int n = 0; n < NNB; ++n)
      xr[n] = *(const float2*)&nb[(n * GG + w) * DIN + 2 * lane];
    float2 xs = *(const float2*)&self_vecs[((size_t)b * GG + w) * DIN + 2 * lane];

    // P1: f-dots (butterfly reduce), lanes<8 write f_s
#pragma unroll
    for (int n = 0; n < NNB; ++n) {
      float acc[8];
#pragma unroll
      for (int h = 0; h < 8; ++h)
        acc[h] = xr[n].x * wn2[h].x + xr[n].y * wn2[h].y;
      float f = hreduce8(acc, lane);
      if (lane < 8) f_s[(bl * 84 + n * 4 + w) * 8 + hm] = f;
    }
    {
      float acc[8];
#pragma unroll
      for (int h = 0; h < 8; ++h)
        acc[h] = xs.x * ws2[h].x + xs.y * ws2[h].y;
      float f = hreduce8(acc, lane);
      if (lane < 8) f_s[(bl * 84 + 80 + w) * 8 + hm] = f;
    }
    __syncthreads();   // all waves' f_s[bl] visible

    // P2 (per-wave redundant): this wave computes att for its own g=w only.
#pragma unroll
    for (int it = 0; it < 3; ++it) {
      int task = lane + it * 64;
      if (task < 160) {
        int n = task >> 3, h = task & 7;
        float l[4], m = -1e30f;
#pragma unroll
        for (int gg = 0; gg < 4; ++gg) {
          float v = lrelu_f(f_s[(bl * 84 + 80 + gg) * 8 + h] + f_s[(bl * 84 + n * 4 + gg) * 8 + h]);
          l[gg] = v;
          m = fmaxf(m, v);
        }
        float s = 0.f;
#pragma unroll
        for (int gg = 0; gg < 4; ++gg) { l[gg] = __expf(l[gg] - m); s += l[gg]; }
        float inv = 1.f / s;
        att_s[bl * 640 + (n * 4 + w) * 8 + h] = l[w] * inv;
      }
    }
    // same-wave LDS RAW: compiler inserts lgkmcnt wait; no barrier needed.

    // P3: agg row (bl*4+w) over n; x already in regs
    {
      float acc[8][2];
#pragma unroll
      for (int h = 0; h < 8; ++h) { acc[h][0] = 0.f; acc[h][1] = 0.f; }
#pragma unroll
      for (int n = 0; n < NNB; ++n) {
        const float* at = &att_s[bl * 640 + (n * 4 + w) * 8];
#pragma unroll
        for (int h = 0; h < 8; ++h) {
          float a = at[h];
          acc[h][0] = fmaf(a, xr[n].x, acc[h][0]);
          acc[h][1] = fmaf(a, xr[n].y, acc[h][1]);
        }
      }
      const int row = bl * 4 + w;
      const int swz = (row & 7) << 4;   // row is wave-uniform
#pragma unroll
      for (int h = 0; h < 8; ++h) {
        unsigned pack = (unsigned)f2bf(acc[h][0]) | ((unsigned)f2bf(acc[h][1]) << 16);
        int byte = (row * 2048 + h * 256 + 4 * lane) ^ swz;
        *(unsigned*)(aggb + byte) = pack;
      }
    }
  }
  __syncthreads();   // agg tile complete; f_s/att_s dead -> hb reuse safe

  // ======== phase B: per-head transform, wave w handles h in {2w, 2w+1} ========
  {
    const int m_ = lane & 15, kg = lane >> 4;
    const int aswz = (m_ & 7) << 4;
#pragma unroll
    for (int hi_ = 0; hi_ < 2; ++hi_) {
      const int hh = 2 * w + hi_;
      bf16x8 a[4];
#pragma unroll
      for (int kb = 0; kb < 4; ++kb) {
        int byte = (m_ * 2048 + hh * 256 + kb * 64 + kg * 16) ^ aswz;
        a[kb] = *(const bf16x8*)(aggb + byte);
      }
#pragma unroll
      for (int nt = 0; nt < 4; ++nt) {
        f32x4 c = {0.f, 0.f, 0.f, 0.f};
#pragma unroll
        for (int kb = 0; kb < 4; ++kb) {
          const int fi = (((hh * 4 + nt) * 4 + kb) * 64 + lane) * 8;
          bf16x8 bh = *(const bf16x8*)(WBhi + fi);
          bf16x8 bl_ = *(const bf16x8*)(WBlo + fi);
          c = __builtin_amdgcn_mfma_f32_16x16x32_bf16(a[kb], bh, c, 0, 0, 0);
          c = __builtin_amdgcn_mfma_f32_16x16x32_bf16(a[kb], bl_, c, 0, 0, 0);
        }
        const int k = hh * 64 + nt * 16 + m_;
#pragma unroll
        for (int reg = 0; reg < 4; ++reg) {
          int lr = kg * 4 + reg;
          int byte = (lr * 2048 + k * 4) ^ ((lr & 7) << 4);
          *(float*)(hb + byte) = lrelu_f(c[reg]);
        }
      }
    }
  }
  __syncthreads();   // h tile complete (all h's, cross-wave)

  // ======== phase C: final FC, wave w owns nt = w ========
  {
    const int m_ = lane & 15, kg = lane >> 4;
    const int swz = (m_ & 7) << 4;
    f32x4 acc = {0.f, 0.f, 0.f, 0.f};
    for (int kb = 0; kb < 16; ++kb) {
      const int base = m_ * 2048 + (kb * 32 + kg * 8) * 4;
      float4 f0 = *(const float4*)(hb + ((base)      ^ swz));
      float4 f1 = *(const float4*)(hb + ((base + 16) ^ swz));
      float fv[8] = {f0.x, f0.y, f0.z, f0.w, f1.x, f1.y, f1.z, f1.w};
      bf16x8 ahi, alo;
#pragma unroll
      for (int j = 0; j < 8; ++j) {
        unsigned short hi = f2bf(fv[j]);
        unsigned short lo = f2bf(fv[j] - bf2f(hi));
        ahi[j] = (short)hi;
        alo[j] = (short)lo;
      }
      const int fi = ((w * 16 + kb) * 64 + lane) * 8;
      bf16x8 bh = *(const bf16x8*)(WOhi + fi);
      bf16x8 bl_ = *(const bf16x8*)(WOlo + fi);
      acc = __builtin_amdgcn_mfma_f32_16x16x32_bf16(ahi, bh, acc, 0, 0, 0);
      acc = __builtin_amdgcn_mfma_f32_16x16x32_bf16(ahi, bl_, acc, 0, 0, 0);
      acc = __builtin_amdgcn_mfma_f32_16x16x32_bf16(alo, bh, acc, 0, 0, 0);
    }
    const int rbase = bid * 16;
#pragma unroll
    for (int reg = 0; reg < 4; ++reg) {
      int row = rbase + kg * 4 + reg;
      out[(size_t)row * EE + w * 16 + m_] = fmaxf(acc[reg], 0.f);
    }
  }
}

extern "C" void kernel_launch(void* const* d_in, const int* in_sizes, int n_in,
                              void* d_out, int out_size, void* d_ws, size_t ws_size,
                              hipStream_t stream) {
  (void)in_sizes; (void)n_in; (void)out_size; (void)ws_size;
  const float* self_vecs  = (const float*)d_in[0];
  const float* neigh_vecs = (const float*)d_in[1];
  const float* W_heads    = (const float*)d_in[2];
  const float* a_self     = (const float*)d_in[3];
  const float* a_neigh    = (const float*)d_in[4];
  const float* W_out      = (const float*)d_in[5];
  float* out              = (float*)d_out;

  char* ws = (char*)d_ws;
  float* w_neigh = (float*)ws;                               // 4 KB
  float* w_self  = (float*)(ws + 4096);                      // 4 KB
  unsigned short* WBhi = (unsigned short*)(ws + 8192);       // 128 KB
  unsigned short* WBlo = (unsigned short*)(ws + 8192 + 131072);
  unsigned short* WOhi = (unsigned short*)(ws + 8192 + 262144);   // 64 KB
  unsigned short* WOlo = (unsigned short*)(ws + 8192 + 262144 + 65536);

  prep_kernel<<<(2048 + 65536 + 32768 + 255) / 256, 256, 0, stream>>>(
      W_heads, a_self, a_neigh, W_out, w_neigh, w_self, WBhi, WBlo, WOhi, WOlo);

  fused_kernel<<<BB / 4, 256, 0, stream>>>(
      self_vecs, neigh_vecs, w_neigh, w_self, WBhi, WBlo, WOhi, WOlo, out);
}

// Round 8
// 76.546 us; speedup vs baseline: 3.8188x; 1.4409x over previous
//
#include <hip/hip_runtime.h>
#include <hip/hip_bf16.h>

#define BB 4096
#define NNB 20
#define GG 4
#define DIN 128
#define EE 64
#define HH 8

typedef short bf16x8 __attribute__((ext_vector_type(8)));
typedef float f32x4 __attribute__((ext_vector_type(4)));

__device__ __forceinline__ float lrelu_f(float x) { return x > 0.f ? x : 0.2f * x; }
__device__ __forceinline__ unsigned short f2bf(float f) {
  unsigned u = __float_as_uint(f);
  return (unsigned short)((u + 0x7fffu + ((u >> 16) & 1u)) >> 16);
}
__device__ __forceinline__ float bf2f(unsigned short s) {
  return __uint_as_float(((unsigned)s) << 16);
}

// ---------------- K0: prep ----------------
// [0,2048):            P1 B-frag (16 cols = 8 w_neigh heads | 8 w_self heads), hi/lo.
//                      id = (kb*64+lane)*8+j ; col=lane&15, k=kb*32+(lane>>4)*8+j
// [2048, +65536):      WB frag-packed hi/lo (phase B weights)
// [2048+65536,+32768): WO frag-packed hi/lo (phase C weights)
__global__ __launch_bounds__(256) void prep_kernel(
    const float* __restrict__ W_heads, const float* __restrict__ a_self,
    const float* __restrict__ a_neigh, const float* __restrict__ W_out,
    unsigned short* __restrict__ P1Whi, unsigned short* __restrict__ P1Wlo,
    unsigned short* __restrict__ WBhi, unsigned short* __restrict__ WBlo,
    unsigned short* __restrict__ WOhi, unsigned short* __restrict__ WOlo) {
  int id = blockIdx.x * 256 + threadIdx.x;
  if (id < 2048) {
    int j = id & 7, lane = (id >> 3) & 63, kb = id >> 9;
    int col = lane & 15, k = kb * 32 + (lane >> 4) * 8 + j;
    int h = col & 7;
    const float* a = (col < 8) ? a_neigh : a_self;
    const float* Wrow = W_heads + (h * DIN + k) * EE;
    float acc = 0.f;
    for (int e = 0; e < EE; ++e) acc = fmaf(Wrow[e], a[h * EE + e], acc);
    unsigned short hi = f2bf(acc);
    P1Whi[id] = hi;
    P1Wlo[id] = f2bf(acc - bf2f(hi));
  } else if (id < 2048 + 65536) {
    int rel = id - 2048;   // (((h*4+nt)*4+kb)*64 + l)*8 + j
    int j = rel & 7, l = (rel >> 3) & 63, kb = (rel >> 9) & 3, nt = (rel >> 11) & 3, h = rel >> 13;
    int d = kb * 32 + (l >> 4) * 8 + j;
    int e = nt * 16 + (l & 15);
    float w = W_heads[(h * DIN + d) * EE + e];
    unsigned short hi = f2bf(w);
    WBhi[rel] = hi;
    WBlo[rel] = f2bf(w - bf2f(hi));
  } else if (id < 2048 + 65536 + 32768) {
    int rel = id - 2048 - 65536;  // ((nt*16+kb)*64 + l)*8 + j
    int j = rel & 7, l = (rel >> 3) & 63, kb = (rel >> 9) & 15, nt = rel >> 13;
    int k = kb * 32 + (l >> 4) * 8 + j;
    int n = nt * 16 + (l & 15);
    float w = W_out[k * EE + n];
    unsigned short hi = f2bf(w);
    WOhi[rel] = hi;
    WOlo[rel] = f2bf(w - bf2f(hi));
  }
}

// ---------------- Fused kernel: block = 4 b's = 16 (b,g) rows ----------------
// LDS (64 KB):
//   [0,32768):  agg_s bf16 [bg][h][d], byte ^ ((bg&7)<<4)
//   [32768,65536): union of
//     attn phase: f_s f32 [tile21][bg16][col16] (21504 B) + att_s f32 [n20][bg16][h8] (10240 B)
//     mfma phase: hb f32 [bg16][k512], byte ^ ((row&7)<<4)
// P1 tile mapping: tile t in 0..19 = neighbor n (t), tile 20 = self.
//   A-row (lane&15) = bg = bl*4+g  ->  one MFMA row-tile spans all 4 b's of the block.
__global__ __launch_bounds__(256) void fused_kernel(
    const float* __restrict__ self_vecs, const float* __restrict__ neigh_vecs,
    const unsigned short* __restrict__ P1Whi, const unsigned short* __restrict__ P1Wlo,
    const unsigned short* __restrict__ WBhi, const unsigned short* __restrict__ WBlo,
    const unsigned short* __restrict__ WOhi, const unsigned short* __restrict__ WOlo,
    float* __restrict__ out) {
  __shared__ char smem[65536];
  char* aggb = smem;
  float* f_s   = (float*)(smem + 32768);            // [t][bg][col]
  float* att_s = (float*)(smem + 32768 + 21504);    // [n][bg][h]
  char* hb = smem + 32768;

  const int t = threadIdx.x;
  const int w = t >> 6, lane = t & 63;
  const int m = lane & 15, kg = lane >> 4;
  const int bid = blockIdx.x;

  // P1 weight frags -> regs (B operand, constant across tiles)
  bf16x8 wfh[4], wfl[4];
#pragma unroll
  for (int kb = 0; kb < 4; ++kb) {
    wfh[kb] = *(const bf16x8*)(P1Whi + (kb * 64 + lane) * 8);
    wfl[kb] = *(const bf16x8*)(P1Wlo + (kb * 64 + lane) * 8);
  }

  // ======== P1: f = X_cat x W_cat via MFMA straight from global ========
  const int bl_m = m >> 2, g_m = m & 3;   // this lane's A-row = (bl_m, g_m)
  for (int tile = w; tile < 21; tile += 4) {
    const float* rowp;
    if (tile < 20)
      rowp = neigh_vecs + (((size_t)(bid * 4 + bl_m) * NNB + tile) * GG + g_m) * DIN;
    else
      rowp = self_vecs + ((size_t)bid * 16 + m) * DIN;
    f32x4 c = {0.f, 0.f, 0.f, 0.f};
#pragma unroll
    for (int kb = 0; kb < 4; ++kb) {
      float4 xa = *(const float4*)(rowp + kb * 32 + kg * 8);
      float4 xb = *(const float4*)(rowp + kb * 32 + kg * 8 + 4);
      float xv[8] = {xa.x, xa.y, xa.z, xa.w, xb.x, xb.y, xb.z, xb.w};
      bf16x8 xh, xl;
#pragma unroll
      for (int j = 0; j < 8; ++j) {
        unsigned short hi = f2bf(xv[j]);
        xh[j] = (short)hi;
        xl[j] = (short)f2bf(xv[j] - bf2f(hi));
      }
      c = __builtin_amdgcn_mfma_f32_16x16x32_bf16(xh, wfh[kb], c, 0, 0, 0);
      c = __builtin_amdgcn_mfma_f32_16x16x32_bf16(xh, wfl[kb], c, 0, 0, 0);
      c = __builtin_amdgcn_mfma_f32_16x16x32_bf16(xl, wfh[kb], c, 0, 0, 0);
    }
    // D: col = lane&15 = head-col, row = kg*4+reg = bg
#pragma unroll
    for (int reg = 0; reg < 4; ++reg)
      f_s[tile * 256 + (kg * 4 + reg) * 16 + m] = c[reg];
  }
  __syncthreads();

  // ======== P2: leaky-relu + softmax over g, for each (bl, n, h) ========
#pragma unroll
  for (int it = 0; it < 3; ++it) {
    int task = t + it * 256;               // task = (n*8+h)*4 + bl
    if (task < 640) {
      int bl = task & 3, nh = task >> 2, n = nh >> 3, h = nh & 7;
      float l[4], mx = -1e30f;
#pragma unroll
      for (int gg = 0; gg < 4; ++gg) {
        int bg = bl * 4 + gg;
        float v = lrelu_f(f_s[20 * 256 + bg * 16 + 8 + h] + f_s[n * 256 + bg * 16 + h]);
        l[gg] = v;
        mx = fmaxf(mx, v);
      }
      float s = 0.f;
#pragma unroll
      for (int gg = 0; gg < 4; ++gg) { l[gg] = __expf(l[gg] - mx); s += l[gg]; }
      float inv = 1.f / s;
#pragma unroll
      for (int gg = 0; gg < 4; ++gg) att_s[n * 128 + (bl * 4 + gg) * 8 + h] = l[gg] * inv;
    }
  }
  __syncthreads();

  // ======== P3: agg[bg][h][d] = sum_n att*x (f32 VALU); wave w -> bl = w ========
  {
    const float* nbw = neigh_vecs + (size_t)(bid * 4 + w) * (NNB * GG * DIN);
#pragma unroll
    for (int g = 0; g < 4; ++g) {
      const int bg = w * 4 + g;
      float acc[8][2];
#pragma unroll
      for (int h = 0; h < 8; ++h) { acc[h][0] = 0.f; acc[h][1] = 0.f; }
      for (int n = 0; n < NNB; ++n) {
        float2 x2 = *(const float2*)&nbw[(n * GG + g) * DIN + 2 * lane];
        f32x4 a0 = *(const f32x4*)&att_s[n * 128 + bg * 8];      // uniform addr -> broadcast
        f32x4 a1 = *(const f32x4*)&att_s[n * 128 + bg * 8 + 4];
#pragma unroll
        for (int h = 0; h < 4; ++h) {
          acc[h][0] = fmaf(a0[h], x2.x, acc[h][0]);
          acc[h][1] = fmaf(a0[h], x2.y, acc[h][1]);
          acc[h + 4][0] = fmaf(a1[h], x2.x, acc[h + 4][0]);
          acc[h + 4][1] = fmaf(a1[h], x2.y, acc[h + 4][1]);
        }
      }
      const int swz = (bg & 7) << 4;
#pragma unroll
      for (int h = 0; h < 8; ++h) {
        unsigned pack = (unsigned)f2bf(acc[h][0]) | ((unsigned)f2bf(acc[h][1]) << 16);
        *(unsigned*)(aggb + ((bg * 2048 + h * 256 + 4 * lane) ^ swz)) = pack;
      }
    }
  }
  __syncthreads();   // agg complete; f_s/att_s dead -> hb reuse safe

  // ======== phase B: per-head transform (R7-verified), wave w -> hh in {2w,2w+1} ========
  {
    const int aswz = (m & 7) << 4;
#pragma unroll
    for (int hi_ = 0; hi_ < 2; ++hi_) {
      const int hh = 2 * w + hi_;
      bf16x8 a[4];
#pragma unroll
      for (int kb = 0; kb < 4; ++kb)
        a[kb] = *(const bf16x8*)(aggb + ((m * 2048 + hh * 256 + kb * 64 + kg * 16) ^ aswz));
#pragma unroll
      for (int nt = 0; nt < 4; ++nt) {
        f32x4 c = {0.f, 0.f, 0.f, 0.f};
#pragma unroll
        for (int kb = 0; kb < 4; ++kb) {
          const int fi = (((hh * 4 + nt) * 4 + kb) * 64 + lane) * 8;
          bf16x8 bh = *(const bf16x8*)(WBhi + fi);
          bf16x8 bl_ = *(const bf16x8*)(WBlo + fi);
          c = __builtin_amdgcn_mfma_f32_16x16x32_bf16(a[kb], bh, c, 0, 0, 0);
          c = __builtin_amdgcn_mfma_f32_16x16x32_bf16(a[kb], bl_, c, 0, 0, 0);
        }
        const int k = hh * 64 + nt * 16 + m;
#pragma unroll
        for (int reg = 0; reg < 4; ++reg) {
          int lr = kg * 4 + reg;
          int byte = (lr * 2048 + k * 4) ^ ((lr & 7) << 4);
          *(float*)(hb + byte) = lrelu_f(c[reg]);
        }
      }
    }
  }
  __syncthreads();

  // ======== phase C: final FC (R7-verified), wave w owns nt = w ========
  {
    const int swz = (m & 7) << 4;
    f32x4 acc = {0.f, 0.f, 0.f, 0.f};
    for (int kb = 0; kb < 16; ++kb) {
      const int base = m * 2048 + (kb * 32 + kg * 8) * 4;
      float4 f0 = *(const float4*)(hb + ((base)      ^ swz));
      float4 f1 = *(const float4*)(hb + ((base + 16) ^ swz));
      float fv[8] = {f0.x, f0.y, f0.z, f0.w, f1.x, f1.y, f1.z, f1.w};
      bf16x8 ahi, alo;
#pragma unroll
      for (int j = 0; j < 8; ++j) {
        unsigned short hi = f2bf(fv[j]);
        ahi[j] = (short)hi;
        alo[j] = (short)f2bf(fv[j] - bf2f(hi));
      }
      const int fi = ((w * 16 + kb) * 64 + lane) * 8;
      bf16x8 bh = *(const bf16x8*)(WOhi + fi);
      bf16x8 bl_ = *(const bf16x8*)(WOlo + fi);
      acc = __builtin_amdgcn_mfma_f32_16x16x32_bf16(ahi, bh, acc, 0, 0, 0);
      acc = __builtin_amdgcn_mfma_f32_16x16x32_bf16(ahi, bl_, acc, 0, 0, 0);
      acc = __builtin_amdgcn_mfma_f32_16x16x32_bf16(alo, bh, acc, 0, 0, 0);
    }
    const int rbase = bid * 16;
#pragma unroll
    for (int reg = 0; reg < 4; ++reg) {
      int row = rbase + kg * 4 + reg;
      out[(size_t)row * EE + w * 16 + m] = fmaxf(acc[reg], 0.f);
    }
  }
}

extern "C" void kernel_launch(void* const* d_in, const int* in_sizes, int n_in,
                              void* d_out, int out_size, void* d_ws, size_t ws_size,
                              hipStream_t stream) {
  (void)in_sizes; (void)n_in; (void)out_size; (void)ws_size;
  const float* self_vecs  = (const float*)d_in[0];
  const float* neigh_vecs = (const float*)d_in[1];
  const float* W_heads    = (const float*)d_in[2];
  const float* a_self     = (const float*)d_in[3];
  const float* a_neigh    = (const float*)d_in[4];
  const float* W_out      = (const float*)d_in[5];
  float* out              = (float*)d_out;

  char* ws = (char*)d_ws;
  unsigned short* P1Whi = (unsigned short*)ws;                    // 4 KB
  unsigned short* P1Wlo = (unsigned short*)(ws + 4096);           // 4 KB
  unsigned short* WBhi  = (unsigned short*)(ws + 8192);           // 128 KB
  unsigned short* WBlo  = (unsigned short*)(ws + 8192 + 131072);
  unsigned short* WOhi  = (unsigned short*)(ws + 8192 + 262144);  // 64 KB
  unsigned short* WOlo  = (unsigned short*)(ws + 8192 + 262144 + 65536);

  prep_kernel<<<(2048 + 65536 + 32768) / 256, 256, 0, stream>>>(
      W_heads, a_self, a_neigh, W_out, P1Whi, P1Wlo, WBhi, WBlo, WOhi, WOlo);

  fused_kernel<<<BB / 4, 256, 0, stream>>>(
      self_vecs, neigh_vecs, P1Whi, P1Wlo, WBhi, WBlo, WOhi, WOlo, out);
}

// Round 9
// 67.857 us; speedup vs baseline: 4.3078x; 1.1280x over previous
//
#include <hip/hip_runtime.h>
#include <hip/hip_bf16.h>

#define BB 4096
#define NNB 20
#define GG 4
#define DIN 128
#define EE 64
#define HH 8

typedef short bf16x8 __attribute__((ext_vector_type(8)));
typedef float f32x4 __attribute__((ext_vector_type(4)));

__device__ __forceinline__ float lrelu_f(float x) { return x > 0.f ? x : 0.2f * x; }
__device__ __forceinline__ unsigned short f2bf(float f) {
  unsigned u = __float_as_uint(f);
  return (unsigned short)((u + 0x7fffu + ((u >> 16) & 1u)) >> 16);
}
__device__ __forceinline__ float bf2f(unsigned short s) {
  return __uint_as_float(((unsigned)s) << 16);
}

// ---------------- K0: prep (unchanged from R8) ----------------
__global__ __launch_bounds__(256) void prep_kernel(
    const float* __restrict__ W_heads, const float* __restrict__ a_self,
    const float* __restrict__ a_neigh, const float* __restrict__ W_out,
    unsigned short* __restrict__ P1Whi, unsigned short* __restrict__ P1Wlo,
    unsigned short* __restrict__ WBhi, unsigned short* __restrict__ WBlo,
    unsigned short* __restrict__ WOhi, unsigned short* __restrict__ WOlo) {
  int id = blockIdx.x * 256 + threadIdx.x;
  if (id < 2048) {
    int j = id & 7, lane = (id >> 3) & 63, kb = id >> 9;
    int col = lane & 15, k = kb * 32 + (lane >> 4) * 8 + j;
    int h = col & 7;
    const float* a = (col < 8) ? a_neigh : a_self;
    const float* Wrow = W_heads + (h * DIN + k) * EE;
    float acc = 0.f;
    for (int e = 0; e < EE; ++e) acc = fmaf(Wrow[e], a[h * EE + e], acc);
    unsigned short hi = f2bf(acc);
    P1Whi[id] = hi;
    P1Wlo[id] = f2bf(acc - bf2f(hi));
  } else if (id < 2048 + 65536) {
    int rel = id - 2048;   // (((h*4+nt)*4+kb)*64 + l)*8 + j
    int j = rel & 7, l = (rel >> 3) & 63, kb = (rel >> 9) & 3, nt = (rel >> 11) & 3, h = rel >> 13;
    int d = kb * 32 + (l >> 4) * 8 + j;
    int e = nt * 16 + (l & 15);
    float w = W_heads[(h * DIN + d) * EE + e];
    unsigned short hi = f2bf(w);
    WBhi[rel] = hi;
    WBlo[rel] = f2bf(w - bf2f(hi));
  } else if (id < 2048 + 65536 + 32768) {
    int rel = id - 2048 - 65536;  // ((nt*16+kb)*64 + l)*8 + j
    int j = rel & 7, l = (rel >> 3) & 63, kb = (rel >> 9) & 15, nt = rel >> 13;
    int k = kb * 32 + (l >> 4) * 8 + j;
    int n = nt * 16 + (l & 15);
    float w = W_out[k * EE + n];
    unsigned short hi = f2bf(w);
    WOhi[rel] = hi;
    WOlo[rel] = f2bf(w - bf2f(hi));
  }
}

// ---------------- Fused kernel: 512 threads (8 waves), 4 b's = 16 bg rows ----------------
// LDS 53,760 B:
//   [0,32768):       agg bf16 [bg16][h8][d128], byte ^ ((bg&7)<<4)
//   [32768,43520):   f_n f32, word = tile*128 + ((row*8+col) ^ ((row>>2)<<3))
//                    tiles 0..19: col = neigh head; tile 20: col = self head
//   [43520,53760):   att f32, word = n*128 + ((bg*8+h) ^ ((bg>>2)<<3))
//   [32768,49152):   h_s bf16 [row16][k512], byte ^ ((row&7)<<4)   (reuses f/att after P3)
__global__ __launch_bounds__(512, 4) void fused_kernel(
    const float* __restrict__ self_vecs, const float* __restrict__ neigh_vecs,
    const unsigned short* __restrict__ P1Whi, const unsigned short* __restrict__ P1Wlo,
    const unsigned short* __restrict__ WBhi, const unsigned short* __restrict__ WBlo,
    const unsigned short* __restrict__ WOhi, const unsigned short* __restrict__ WOlo,
    float* __restrict__ out) {
  __shared__ char smem[53760];
  char* aggb = smem;
  float* fw   = (float*)(smem + 32768);   // f_n words
  float* attw = (float*)(smem + 43520);   // att words
  char* hb = smem + 32768;                // h_s bytes (reuse)

  const int t = threadIdx.x;
  const int w = t >> 6, lane = t & 63;
  const int m = lane & 15, kg = lane >> 4;
  const int bid = blockIdx.x;

  // P1 weight frags (B operand)
  bf16x8 wfh[4], wfl[4];
#pragma unroll
  for (int kb = 0; kb < 4; ++kb) {
    wfh[kb] = *(const bf16x8*)(P1Whi + (kb * 64 + lane) * 8);
    wfl[kb] = *(const bf16x8*)(P1Wlo + (kb * 64 + lane) * 8);
  }

  // ======== P1: f = X_cat x W_cat via MFMA straight from global ========
  const int bl_m = m >> 2, g_m = m & 3;
  for (int tile = w; tile < 21; tile += 8) {
    const float* rowp;
    if (tile < 20)
      rowp = neigh_vecs + (((size_t)(bid * 4 + bl_m) * NNB + tile) * GG + g_m) * DIN;
    else
      rowp = self_vecs + ((size_t)bid * 16 + m) * DIN;
    f32x4 c = {0.f, 0.f, 0.f, 0.f};
#pragma unroll
    for (int kb = 0; kb < 4; ++kb) {
      float4 xa = *(const float4*)(rowp + kb * 32 + kg * 8);
      float4 xb = *(const float4*)(rowp + kb * 32 + kg * 8 + 4);
      float xv[8] = {xa.x, xa.y, xa.z, xa.w, xb.x, xb.y, xb.z, xb.w};
      bf16x8 xh, xl;
#pragma unroll
      for (int j = 0; j < 8; ++j) {
        unsigned short hi = f2bf(xv[j]);
        xh[j] = (short)hi;
        xl[j] = (short)f2bf(xv[j] - bf2f(hi));
      }
      c = __builtin_amdgcn_mfma_f32_16x16x32_bf16(xh, wfh[kb], c, 0, 0, 0);
      c = __builtin_amdgcn_mfma_f32_16x16x32_bf16(xh, wfl[kb], c, 0, 0, 0);
      c = __builtin_amdgcn_mfma_f32_16x16x32_bf16(xl, wfh[kb], c, 0, 0, 0);
    }
    // D: col = m = head-col, row = kg*4+reg = bg
    if (tile < 20) {
      if (m < 8) {
#pragma unroll
        for (int reg = 0; reg < 4; ++reg) {
          int row = kg * 4 + reg;
          fw[tile * 128 + ((row * 8 + m) ^ (kg << 3))] = c[reg];
        }
      }
    } else {
      if (m >= 8) {
#pragma unroll
        for (int reg = 0; reg < 4; ++reg) {
          int row = kg * 4 + reg;
          fw[20 * 128 + ((row * 8 + (m - 8)) ^ (kg << 3))] = c[reg];
        }
      }
    }
  }
  __syncthreads();

  // ======== P2: leaky-relu + softmax over g ========
#pragma unroll
  for (int it = 0; it < 2; ++it) {
    int task = t + it * 512;           // task = (n*8+h)*4 + bl
    if (task < 640) {
      int bl = task & 3, h = (task >> 2) & 7, n = task >> 5;
      float l[4], mx = -1e30f;
#pragma unroll
      for (int gg = 0; gg < 4; ++gg) {
        int bg = bl * 4 + gg;
        float fn = fw[n * 128 + ((bg * 8 + h) ^ (bl << 3))];
        float fs = fw[20 * 128 + ((bg * 8 + h) ^ (bl << 3))];
        float v = lrelu_f(fs + fn);
        l[gg] = v;
        mx = fmaxf(mx, v);
      }
      float s = 0.f;
#pragma unroll
      for (int gg = 0; gg < 4; ++gg) { l[gg] = __expf(l[gg] - mx); s += l[gg]; }
      float inv = 1.f / s;
#pragma unroll
      for (int gg = 0; gg < 4; ++gg)
        attw[n * 128 + (((bl * 4 + gg) * 8 + h) ^ (bl << 3))] = l[gg] * inv;
    }
  }
  __syncthreads();

  // ======== P3: agg[bg][h][d] = sum_n att*x ; wave w -> bg {2w, 2w+1} ========
#pragma unroll
  for (int i = 0; i < 2; ++i) {
    const int bg = 2 * w + i;
    const int bl = bg >> 2, g = bg & 3;
    const float* nbw = neigh_vecs + ((size_t)(bid * 4 + bl) * NNB * GG + g) * DIN;
    float acc[8][2];
#pragma unroll
    for (int h = 0; h < 8; ++h) { acc[h][0] = 0.f; acc[h][1] = 0.f; }
    for (int n = 0; n < NNB; ++n) {
      float2 x2 = *(const float2*)&nbw[(size_t)n * GG * DIN + 2 * lane];
      const int abase = n * 128 + ((bg * 8) ^ (bl << 3));   // uniform -> broadcast
      f32x4 a0 = *(const f32x4*)&attw[abase];
      f32x4 a1 = *(const f32x4*)&attw[abase + 4];
#pragma unroll
      for (int h = 0; h < 4; ++h) {
        acc[h][0] = fmaf(a0[h], x2.x, acc[h][0]);
        acc[h][1] = fmaf(a0[h], x2.y, acc[h][1]);
        acc[h + 4][0] = fmaf(a1[h], x2.x, acc[h + 4][0]);
        acc[h + 4][1] = fmaf(a1[h], x2.y, acc[h + 4][1]);
      }
    }
    const int swz = (bg & 7) << 4;
#pragma unroll
    for (int h = 0; h < 8; ++h) {
      unsigned pack = (unsigned)f2bf(acc[h][0]) | ((unsigned)f2bf(acc[h][1]) << 16);
      *(unsigned*)(aggb + ((bg * 2048 + h * 256 + 4 * lane) ^ swz)) = pack;
    }
  }
  __syncthreads();   // agg complete; f/att dead -> hb reuse

  // ======== phase B: head transform, wave w -> hh = w; h stored bf16 ========
  {
    const int hh = w;
    const int aswz = (m & 7) << 4;
    bf16x8 a[4];
#pragma unroll
    for (int kb = 0; kb < 4; ++kb)
      a[kb] = *(const bf16x8*)(aggb + ((m * 2048 + hh * 256 + kb * 64 + kg * 16) ^ aswz));
#pragma unroll
    for (int nt = 0; nt < 4; ++nt) {
      f32x4 c = {0.f, 0.f, 0.f, 0.f};
#pragma unroll
      for (int kb = 0; kb < 4; ++kb) {
        const int fi = (((hh * 4 + nt) * 4 + kb) * 64 + lane) * 8;
        bf16x8 bh = *(const bf16x8*)(WBhi + fi);
        bf16x8 bl_ = *(const bf16x8*)(WBlo + fi);
        c = __builtin_amdgcn_mfma_f32_16x16x32_bf16(a[kb], bh, c, 0, 0, 0);
        c = __builtin_amdgcn_mfma_f32_16x16x32_bf16(a[kb], bl_, c, 0, 0, 0);
      }
      const int k = hh * 64 + nt * 16 + m;
#pragma unroll
      for (int reg = 0; reg < 4; ++reg) {
        int row = kg * 4 + reg;
        int byte = (row * 1024 + k * 2) ^ ((row & 7) << 4);
        *(unsigned short*)(hb + byte) = f2bf(lrelu_f(c[reg]));
      }
    }
  }
  __syncthreads();

  // ======== phase C: final FC, waves 0..3, nt = w ========
  if (w < 4) {
    const int nt = w;
    f32x4 acc = {0.f, 0.f, 0.f, 0.f};
    for (int kb = 0; kb < 16; ++kb) {
      int byte = (m * 1024 + (kb * 32 + kg * 8) * 2) ^ ((m & 7) << 4);
      bf16x8 ah = *(const bf16x8*)(hb + byte);
      const int fi = ((nt * 16 + kb) * 64 + lane) * 8;
      bf16x8 bh = *(const bf16x8*)(WOhi + fi);
      bf16x8 bl_ = *(const bf16x8*)(WOlo + fi);
      acc = __builtin_amdgcn_mfma_f32_16x16x32_bf16(ah, bh, acc, 0, 0, 0);
      acc = __builtin_amdgcn_mfma_f32_16x16x32_bf16(ah, bl_, acc, 0, 0, 0);
    }
    const int rbase = bid * 16;
#pragma unroll
    for (int reg = 0; reg < 4; ++reg) {
      int row = rbase + kg * 4 + reg;
      out[(size_t)row * EE + nt * 16 + m] = fmaxf(acc[reg], 0.f);
    }
  }
}

extern "C" void kernel_launch(void* const* d_in, const int* in_sizes, int n_in,
                              void* d_out, int out_size, void* d_ws, size_t ws_size,
                              hipStream_t stream) {
  (void)in_sizes; (void)n_in; (void)out_size; (void)ws_size;
  const float* self_vecs  = (const float*)d_in[0];
  const float* neigh_vecs = (const float*)d_in[1];
  const float* W_heads    = (const float*)d_in[2];
  const float* a_self     = (const float*)d_in[3];
  const float* a_neigh    = (const float*)d_in[4];
  const float* W_out      = (const float*)d_in[5];
  float* out              = (float*)d_out;

  char* ws = (char*)d_ws;
  unsigned short* P1Whi = (unsigned short*)ws;                    // 4 KB
  unsigned short* P1Wlo = (unsigned short*)(ws + 4096);           // 4 KB
  unsigned short* WBhi  = (unsigned short*)(ws + 8192);           // 128 KB
  unsigned short* WBlo  = (unsigned short*)(ws + 8192 + 131072);
  unsigned short* WOhi  = (unsigned short*)(ws + 8192 + 262144);  // 64 KB
  unsigned short* WOlo  = (unsigned short*)(ws + 8192 + 262144 + 65536);

  prep_kernel<<<(2048 + 65536 + 32768) / 256, 256, 0, stream>>>(
      W_heads, a_self, a_neigh, W_out, P1Whi, P1Wlo, WBhi, WBlo, WOhi, WOlo);

  fused_kernel<<<BB / 4, 512, 0, stream>>>(
      self_vecs, neigh_vecs, P1Whi, P1Wlo, WBhi, WBlo, WOhi, WOlo, out);
}